// Round 1
// baseline (875.468 us; speedup 1.0000x reference)
//
#include <hip/hip_runtime.h>
#include <hip/hip_bf16.h>
#include <math.h>

// Problem constants (from reference): F_IN=256, H=4, C=32, H*C=128
// NEG_SLOPE_ATT=0.2, NEG_SLOPE_ACT=0.01, EPS=1e-5
// bias is skipped: BN batch-stats subtract it out exactly.

// ---------------- GEMM: h[n][128] = x[n][256] @ W[128][256]^T ----------------
__global__ __launch_bounds__(256) void gemm_xwt(const float* __restrict__ x,
                                                const float* __restrict__ w,
                                                float* __restrict__ hout, int n) {
  __shared__ float xs[32][64];    // [k][row]
  __shared__ float wsl[32][128];  // [k][col]
  int tid = threadIdx.x;
  int row0 = blockIdx.x * 64;
  int rg = tid >> 5;   // 0..7 -> rows rg*8 .. rg*8+7
  int cg = tid & 31;   // cols cg*4 .. cg*4+3
  float acc[8][4];
#pragma unroll
  for (int i = 0; i < 8; i++)
#pragma unroll
    for (int j = 0; j < 4; j++) acc[i][j] = 0.f;

  for (int kk = 0; kk < 256; kk += 32) {
    __syncthreads();
    // x tile: 64 rows x 32 k = 512 float4, 2 per thread, store transposed
#pragma unroll
    for (int i = 0; i < 2; i++) {
      int f4 = tid + i * 256;      // 0..511
      int r = f4 >> 3;             // row in tile
      int k4 = f4 & 7;             // float4 index along k
      int grow = row0 + r;
      float4 v = make_float4(0.f, 0.f, 0.f, 0.f);
      if (grow < n) v = *(const float4*)&x[(size_t)grow * 256 + kk + k4 * 4];
      xs[k4 * 4 + 0][r] = v.x;
      xs[k4 * 4 + 1][r] = v.y;
      xs[k4 * 4 + 2][r] = v.z;
      xs[k4 * 4 + 3][r] = v.w;
    }
    // W tile: 128 cols x 32 k = 1024 float4, 4 per thread, store transposed
#pragma unroll
    for (int i = 0; i < 4; i++) {
      int f4 = tid + i * 256;      // 0..1023
      int c = f4 >> 3;
      int k4 = f4 & 7;
      float4 v = *(const float4*)&w[(size_t)c * 256 + kk + k4 * 4];
      wsl[k4 * 4 + 0][c] = v.x;
      wsl[k4 * 4 + 1][c] = v.y;
      wsl[k4 * 4 + 2][c] = v.z;
      wsl[k4 * 4 + 3][c] = v.w;
    }
    __syncthreads();
#pragma unroll
    for (int k = 0; k < 32; ++k) {
      float4 a0 = *(const float4*)&xs[k][rg * 8];
      float4 a1 = *(const float4*)&xs[k][rg * 8 + 4];
      float4 bv = *(const float4*)&wsl[k][cg * 4];
      float av[8] = {a0.x, a0.y, a0.z, a0.w, a1.x, a1.y, a1.z, a1.w};
      float bb[4] = {bv.x, bv.y, bv.z, bv.w};
#pragma unroll
      for (int i = 0; i < 8; i++)
#pragma unroll
        for (int j = 0; j < 4; j++) acc[i][j] = fmaf(av[i], bb[j], acc[i][j]);
    }
  }
#pragma unroll
  for (int i = 0; i < 8; i++) {
    int grow = row0 + rg * 8 + i;
    if (grow < n)
      *(float4*)&hout[(size_t)grow * 128 + cg * 4] =
          make_float4(acc[i][0], acc[i][1], acc[i][2], acc[i][3]);
  }
}

// ------------- per-node attention scores: a_s[n][4], a_d[n][4] -------------
__global__ __launch_bounds__(256) void att_scores(const float* __restrict__ h,
                                                  const float* __restrict__ att_s,
                                                  const float* __restrict__ att_d,
                                                  float* __restrict__ a_s,
                                                  float* __restrict__ a_d, int n) {
  int wave = (blockIdx.x * 256 + threadIdx.x) >> 6;
  int lane = threadIdx.x & 63;
  if (wave >= n) return;
  float h0 = h[(size_t)wave * 128 + lane];
  float h1 = h[(size_t)wave * 128 + 64 + lane];
  float s0 = h0 * att_s[lane], s1 = h1 * att_s[64 + lane];
  float d0 = h0 * att_d[lane], d1 = h1 * att_d[64 + lane];
#pragma unroll
  for (int off = 16; off; off >>= 1) {
    s0 += __shfl_down(s0, off, 32);
    s1 += __shfl_down(s1, off, 32);
    d0 += __shfl_down(d0, off, 32);
    d1 += __shfl_down(d1, off, 32);
  }
  if ((lane & 31) == 0) {
    int half = lane >> 5;  // cols 0..63 -> heads 0,1 ; cols 64..127 -> heads 2,3
    a_s[wave * 4 + half] = s0;
    a_s[wave * 4 + 2 + half] = s1;
    a_d[wave * 4 + half] = d0;
    a_d[wave * 4 + 2 + half] = d1;
  }
}

// ---------------- order-preserving float<->uint for atomicMax ----------------
__device__ inline unsigned enc_f(float x) {
  unsigned u = __float_as_uint(x);
  return (u & 0x80000000u) ? ~u : (u | 0x80000000u);
}
__device__ inline float dec_f(unsigned u) {
  return __uint_as_float((u & 0x80000000u) ? (u ^ 0x80000000u) : ~u);
}

__device__ inline float lrelu02(float v) { return v > 0.f ? v : 0.2f * v; }

// --------------------------- segment max over dst ---------------------------
__global__ __launch_bounds__(256) void edge_max_k(const int* __restrict__ src,
                                                  const int* __restrict__ dst,
                                                  const float4* __restrict__ a_s,
                                                  const float4* __restrict__ a_d,
                                                  unsigned* __restrict__ emax,
                                                  int E, int n) {
  int i = blockIdx.x * 256 + threadIdx.x;
  if (i >= E + n) return;
  int s, d;
  if (i < E) { s = src[i]; d = dst[i]; } else { s = d = i - E; }
  float4 vs = a_s[s], vd = a_d[d];
  float e0 = lrelu02(vs.x + vd.x), e1 = lrelu02(vs.y + vd.y);
  float e2 = lrelu02(vs.z + vd.z), e3 = lrelu02(vs.w + vd.w);
  atomicMax(&emax[d * 4 + 0], enc_f(e0));
  atomicMax(&emax[d * 4 + 1], enc_f(e1));
  atomicMax(&emax[d * 4 + 2], enc_f(e2));
  atomicMax(&emax[d * 4 + 3], enc_f(e3));
}

// --------------------------- segment sum of exp ---------------------------
__global__ __launch_bounds__(256) void edge_sum_k(const int* __restrict__ src,
                                                  const int* __restrict__ dst,
                                                  const float4* __restrict__ a_s,
                                                  const float4* __restrict__ a_d,
                                                  const unsigned* __restrict__ emax,
                                                  float* __restrict__ denom,
                                                  int E, int n) {
  int i = blockIdx.x * 256 + threadIdx.x;
  if (i >= E + n) return;
  int s, d;
  if (i < E) { s = src[i]; d = dst[i]; } else { s = d = i - E; }
  float4 vs = a_s[s], vd = a_d[d];
  float e0 = lrelu02(vs.x + vd.x), e1 = lrelu02(vs.y + vd.y);
  float e2 = lrelu02(vs.z + vd.z), e3 = lrelu02(vs.w + vd.w);
  atomicAdd(&denom[d * 4 + 0], expf(e0 - dec_f(emax[d * 4 + 0])));
  atomicAdd(&denom[d * 4 + 1], expf(e1 - dec_f(emax[d * 4 + 1])));
  atomicAdd(&denom[d * 4 + 2], expf(e2 - dec_f(emax[d * 4 + 2])));
  atomicAdd(&denom[d * 4 + 3], expf(e3 - dec_f(emax[d * 4 + 3])));
}

// ----------------- aggregation: out[dst] += alpha * h[src] -----------------
// one wave per edge; lane covers cols lane and lane+64
__global__ __launch_bounds__(256) void edge_agg_k(const int* __restrict__ src,
                                                  const int* __restrict__ dst,
                                                  const float* __restrict__ a_s,
                                                  const float* __restrict__ a_d,
                                                  const unsigned* __restrict__ emax,
                                                  const float* __restrict__ denom,
                                                  const float* __restrict__ h,
                                                  float* __restrict__ out,
                                                  int E, int n) {
  int e = (blockIdx.x * 256 + threadIdx.x) >> 6;
  int lane = threadIdx.x & 63;
  if (e >= E + n) return;
  int s, d;
  if (e < E) { s = src[e]; d = dst[e]; } else { s = d = e - E; }
  int h0 = lane >> 5;      // head of col `lane`
  int h1 = h0 + 2;         // head of col `lane+64`
  float e0 = lrelu02(a_s[s * 4 + h0] + a_d[d * 4 + h0]);
  float e1 = lrelu02(a_s[s * 4 + h1] + a_d[d * 4 + h1]);
  float al0 = expf(e0 - dec_f(emax[d * 4 + h0])) / denom[d * 4 + h0];
  float al1 = expf(e1 - dec_f(emax[d * 4 + h1])) / denom[d * 4 + h1];
  atomicAdd(&out[(size_t)d * 128 + lane], al0 * h[(size_t)s * 128 + lane]);
  atomicAdd(&out[(size_t)d * 128 + 64 + lane], al1 * h[(size_t)s * 128 + 64 + lane]);
}

// -------------------------- BatchNorm batch stats --------------------------
__global__ __launch_bounds__(256) void bn_stats_k(const float* __restrict__ out,
                                                  float* __restrict__ sums,
                                                  float* __restrict__ sumsq, int n) {
  int j = threadIdx.x & 127;
  int stream = blockIdx.x * 2 + (threadIdx.x >> 7);
  int stride = gridDim.x * 2;
  float s = 0.f, s2 = 0.f;
  for (int r = stream; r < n; r += stride) {
    float v = out[(size_t)r * 128 + j];
    s += v;
    s2 += v * v;
  }
  atomicAdd(&sums[j], s);
  atomicAdd(&sumsq[j], s2);
}

__global__ void bn_coef_k(const float* __restrict__ sums,
                          const float* __restrict__ sumsq,
                          const float* __restrict__ gamma,
                          const float* __restrict__ beta,
                          float* __restrict__ scale, float* __restrict__ shift,
                          float inv_n) {
  int j = threadIdx.x;
  float mu = sums[j] * inv_n;
  float var = sumsq[j] * inv_n - mu * mu;
  float rstd = 1.0f / sqrtf(var + 1e-5f);
  float g = gamma[j] * rstd;
  scale[j] = g;
  shift[j] = beta[j] - mu * g;
}

// --------------------- normalize + LeakyReLU(0.01), in-place ---------------------
__global__ __launch_bounds__(256) void bn_apply_k(float* __restrict__ out,
                                                  const float* __restrict__ scale,
                                                  const float* __restrict__ shift,
                                                  int n4) {
  int i = blockIdx.x * 256 + threadIdx.x;
  if (i >= n4) return;
  float4 v = ((float4*)out)[i];
  int j = (i & 31) << 2;
  const float4 sc = *(const float4*)&scale[j];
  const float4 sh = *(const float4*)&shift[j];
  v.x = fmaf(v.x, sc.x, sh.x);
  v.y = fmaf(v.y, sc.y, sh.y);
  v.z = fmaf(v.z, sc.z, sh.z);
  v.w = fmaf(v.w, sc.w, sh.w);
  v.x = v.x > 0.f ? v.x : 0.01f * v.x;
  v.y = v.y > 0.f ? v.y : 0.01f * v.y;
  v.z = v.z > 0.f ? v.z : 0.01f * v.z;
  v.w = v.w > 0.f ? v.w : 0.01f * v.w;
  ((float4*)out)[i] = v;
}

extern "C" void kernel_launch(void* const* d_in, const int* in_sizes, int n_in,
                              void* d_out, int out_size, void* d_ws, size_t ws_size,
                              hipStream_t stream) {
  const float* x     = (const float*)d_in[0];
  const int*   ei    = (const int*)d_in[1];
  const float* W     = (const float*)d_in[2];
  const float* att_s = (const float*)d_in[3];
  const float* att_d = (const float*)d_in[4];
  // d_in[5] = bias: cancels exactly under batch-stat BatchNorm -> unused
  const float* gamma = (const float*)d_in[6];
  const float* beta  = (const float*)d_in[7];

  int n = in_sizes[0] / 256;
  int E = in_sizes[1] / 2;
  const int* src = ei;
  const int* dstp = ei + E;
  float* out = (float*)d_out;

  char* p = (char*)d_ws;
  float* h      = (float*)p; p += (size_t)n * 128 * 4;
  float* a_s    = (float*)p; p += (size_t)n * 4 * 4;
  float* a_d    = (float*)p; p += (size_t)n * 4 * 4;
  unsigned* emax= (unsigned*)p; p += (size_t)n * 4 * 4;
  float* denom  = (float*)p; p += (size_t)n * 4 * 4;
  float* sums   = (float*)p; p += 128 * 4;
  float* sumsq  = (float*)p; p += 128 * 4;
  float* scale  = (float*)p; p += 128 * 4;
  float* shift  = (float*)p; p += 128 * 4;

  // zero accumulators (ws/out are poisoned 0xAA before every call)
  hipMemsetAsync(out, 0, (size_t)n * 128 * 4, stream);
  hipMemsetAsync(emax, 0, (size_t)n * 4 * 4, stream);
  hipMemsetAsync(denom, 0, (size_t)n * 4 * 4, stream);
  hipMemsetAsync(sums, 0, 2 * 128 * 4, stream);

  int tot = E + n;
  gemm_xwt<<<(n + 63) / 64, 256, 0, stream>>>(x, W, h, n);
  att_scores<<<(n + 3) / 4, 256, 0, stream>>>(h, att_s, att_d, a_s, a_d, n);
  edge_max_k<<<(tot + 255) / 256, 256, 0, stream>>>(src, dstp, (const float4*)a_s,
                                                    (const float4*)a_d, emax, E, n);
  edge_sum_k<<<(tot + 255) / 256, 256, 0, stream>>>(src, dstp, (const float4*)a_s,
                                                    (const float4*)a_d, emax, denom, E, n);
  edge_agg_k<<<(tot + 3) / 4, 256, 0, stream>>>(src, dstp, a_s, a_d, emax, denom,
                                                h, out, E, n);
  bn_stats_k<<<256, 256, 0, stream>>>(out, sums, sumsq, n);
  bn_coef_k<<<1, 128, 0, stream>>>(sums, sumsq, gamma, beta, scale, shift, 1.0f / n);
  bn_apply_k<<<(n * 32 + 255) / 256, 256, 0, stream>>>(out, scale, shift, n * 32);
}

// Round 2
// 455.109 us; speedup vs baseline: 1.9236x; 1.9236x over previous
//
#include <hip/hip_runtime.h>
#include <hip/hip_bf16.h>
#include <math.h>

// F_IN=256, H=4, C=32, H*C=128; NEG_SLOPE_ATT=0.2, NEG_SLOPE_ACT=0.01, EPS=1e-5
// bias skipped: batch-stat BatchNorm subtracts it exactly.
//
// Round 1 restructure: scatter-atomic aggregation (425 MB atomic writes to HBM)
// replaced by on-device CSR build + one-wave-per-dst fused online-softmax
// aggregation with register accumulation and a single coalesced out write.

__device__ inline float lrelu02(float v) { return v > 0.f ? v : 0.2f * v; }

// ---------------- GEMM: h[n][128] = x[n][256] @ W[128][256]^T ----------------
__global__ __launch_bounds__(256) void gemm_xwt(const float* __restrict__ x,
                                                const float* __restrict__ w,
                                                float* __restrict__ hout, int n) {
  __shared__ float xs[32][64];    // [k][row]
  __shared__ float wsl[32][128];  // [k][col]
  int tid = threadIdx.x;
  int row0 = blockIdx.x * 64;
  int rg = tid >> 5;
  int cg = tid & 31;
  float acc[8][4];
#pragma unroll
  for (int i = 0; i < 8; i++)
#pragma unroll
    for (int j = 0; j < 4; j++) acc[i][j] = 0.f;

  for (int kk = 0; kk < 256; kk += 32) {
    __syncthreads();
#pragma unroll
    for (int i = 0; i < 2; i++) {
      int f4 = tid + i * 256;
      int r = f4 >> 3;
      int k4 = f4 & 7;
      int grow = row0 + r;
      float4 v = make_float4(0.f, 0.f, 0.f, 0.f);
      if (grow < n) v = *(const float4*)&x[(size_t)grow * 256 + kk + k4 * 4];
      xs[k4 * 4 + 0][r] = v.x;
      xs[k4 * 4 + 1][r] = v.y;
      xs[k4 * 4 + 2][r] = v.z;
      xs[k4 * 4 + 3][r] = v.w;
    }
#pragma unroll
    for (int i = 0; i < 4; i++) {
      int f4 = tid + i * 256;
      int c = f4 >> 3;
      int k4 = f4 & 7;
      float4 v = *(const float4*)&w[(size_t)c * 256 + kk + k4 * 4];
      wsl[k4 * 4 + 0][c] = v.x;
      wsl[k4 * 4 + 1][c] = v.y;
      wsl[k4 * 4 + 2][c] = v.z;
      wsl[k4 * 4 + 3][c] = v.w;
    }
    __syncthreads();
#pragma unroll
    for (int k = 0; k < 32; ++k) {
      float4 a0 = *(const float4*)&xs[k][rg * 8];
      float4 a1 = *(const float4*)&xs[k][rg * 8 + 4];
      float4 bv = *(const float4*)&wsl[k][cg * 4];
      float av[8] = {a0.x, a0.y, a0.z, a0.w, a1.x, a1.y, a1.z, a1.w};
      float bb[4] = {bv.x, bv.y, bv.z, bv.w};
#pragma unroll
      for (int i = 0; i < 8; i++)
#pragma unroll
        for (int j = 0; j < 4; j++) acc[i][j] = fmaf(av[i], bb[j], acc[i][j]);
    }
  }
#pragma unroll
  for (int i = 0; i < 8; i++) {
    int grow = row0 + rg * 8 + i;
    if (grow < n)
      *(float4*)&hout[(size_t)grow * 128 + cg * 4] =
          make_float4(acc[i][0], acc[i][1], acc[i][2], acc[i][3]);
  }
}

// ------------- per-node attention scores: a_s[n][4], a_d[n][4] -------------
__global__ __launch_bounds__(256) void att_scores(const float* __restrict__ h,
                                                  const float* __restrict__ att_s,
                                                  const float* __restrict__ att_d,
                                                  float* __restrict__ a_s,
                                                  float* __restrict__ a_d, int n) {
  int wave = (blockIdx.x * 256 + threadIdx.x) >> 6;
  int lane = threadIdx.x & 63;
  if (wave >= n) return;
  float h0 = h[(size_t)wave * 128 + lane];
  float h1 = h[(size_t)wave * 128 + 64 + lane];
  float s0 = h0 * att_s[lane], s1 = h1 * att_s[64 + lane];
  float d0 = h0 * att_d[lane], d1 = h1 * att_d[64 + lane];
#pragma unroll
  for (int off = 16; off; off >>= 1) {
    s0 += __shfl_down(s0, off, 32);
    s1 += __shfl_down(s1, off, 32);
    d0 += __shfl_down(d0, off, 32);
    d1 += __shfl_down(d1, off, 32);
  }
  if ((lane & 31) == 0) {
    int half = lane >> 5;
    a_s[wave * 4 + half] = s0;
    a_s[wave * 4 + 2 + half] = s1;
    a_d[wave * 4 + half] = d0;
    a_d[wave * 4 + 2 + half] = d1;
  }
}

// ------------------------------ CSR build ------------------------------
__global__ __launch_bounds__(256) void deg_init_k(int* __restrict__ deg, int n) {
  int i = blockIdx.x * 256 + threadIdx.x;
  if (i < n) deg[i] = 1;  // self-loop
}

__global__ __launch_bounds__(256) void deg_count_k(const int* __restrict__ dst,
                                                   int* __restrict__ deg, int E) {
  int i = blockIdx.x * 256 + threadIdx.x;
  if (i < E) atomicAdd(&deg[dst[i]], 1);
}

__global__ __launch_bounds__(256) void blocksum_k(const int* __restrict__ deg,
                                                  int* __restrict__ bsum, int n) {
  __shared__ int sd[256];
  int i = blockIdx.x * 256 + threadIdx.x;
  sd[threadIdx.x] = (i < n) ? deg[i] : 0;
  __syncthreads();
  for (int o = 128; o; o >>= 1) {
    if (threadIdx.x < o) sd[threadIdx.x] += sd[threadIdx.x + o];
    __syncthreads();
  }
  if (threadIdx.x == 0) bsum[blockIdx.x] = sd[0];
}

__global__ __launch_bounds__(1024) void scan_bsum_k(int* __restrict__ bsum, int nb) {
  __shared__ int sd[1024];
  int t = threadIdx.x;
  int v = (t < nb) ? bsum[t] : 0;
  sd[t] = v;
  __syncthreads();
  for (int o = 1; o < 1024; o <<= 1) {
    int x = (t >= o) ? sd[t - o] : 0;
    __syncthreads();
    sd[t] += x;
    __syncthreads();
  }
  if (t < nb) bsum[t] = sd[t] - v;  // exclusive
}

__global__ __launch_bounds__(256) void offsets_k(const int* __restrict__ deg,
                                                 const int* __restrict__ bsum,
                                                 int* __restrict__ off,
                                                 int* __restrict__ cur,
                                                 int n, int total) {
  __shared__ int sd[256];
  int t = threadIdx.x;
  int i = blockIdx.x * 256 + t;
  int v = (i < n) ? deg[i] : 0;
  sd[t] = v;
  __syncthreads();
  for (int o = 1; o < 256; o <<= 1) {
    int x = (t >= o) ? sd[t - o] : 0;
    __syncthreads();
    sd[t] += x;
    __syncthreads();
  }
  if (i < n) {
    int ov = bsum[blockIdx.x] + sd[t] - v;
    off[i] = ov;
    cur[i] = ov;
    if (i == n - 1) off[n] = total;
  }
}

__global__ __launch_bounds__(256) void scatter_k(const int* __restrict__ src,
                                                 const int* __restrict__ dst,
                                                 int* __restrict__ cur,
                                                 int* __restrict__ ssrc, int E, int n) {
  int i = blockIdx.x * 256 + threadIdx.x;
  if (i >= E + n) return;
  int s, d;
  if (i < E) { s = src[i]; d = dst[i]; } else { s = d = i - E; }
  int pos = atomicAdd(&cur[d], 1);
  ssrc[pos] = s;
}

// -------- fused online-softmax + aggregation, one wave per dst node --------
__global__ __launch_bounds__(256) void agg_csr_k(const int* __restrict__ off,
                                                 const int* __restrict__ ssrc,
                                                 const float* __restrict__ a_s,
                                                 const float* __restrict__ a_d,
                                                 const float* __restrict__ h,
                                                 float* __restrict__ out, int n) {
  int d = (blockIdx.x * 256 + threadIdx.x) >> 6;
  int lane = threadIdx.x & 63;
  if (d >= n) return;
  int start = off[d];
  int end = off[d + 1];

  float4 ad4 = *(const float4*)&a_d[d * 4];
  float adh[4] = {ad4.x, ad4.y, ad4.z, ad4.w};

  // pass 1: per-head online (m, l) over this node's edges, lanes strided
  float m[4] = {-1e30f, -1e30f, -1e30f, -1e30f};
  float l[4] = {0.f, 0.f, 0.f, 0.f};
  for (int j = start + lane; j < end; j += 64) {
    int s = ssrc[j];
    float4 as4 = *(const float4*)&a_s[s * 4];
    float e[4] = {lrelu02(as4.x + adh[0]), lrelu02(as4.y + adh[1]),
                  lrelu02(as4.z + adh[2]), lrelu02(as4.w + adh[3])};
#pragma unroll
    for (int hh = 0; hh < 4; hh++) {
      float nm = fmaxf(m[hh], e[hh]);
      l[hh] = l[hh] * expf(m[hh] - nm) + expf(e[hh] - nm);
      m[hh] = nm;
    }
  }
  // butterfly merge across 64 lanes
#pragma unroll
  for (int hh = 0; hh < 4; hh++) {
#pragma unroll
    for (int o = 1; o < 64; o <<= 1) {
      float om = __shfl_xor(m[hh], o, 64);
      float ol = __shfl_xor(l[hh], o, 64);
      float nm = fmaxf(m[hh], om);
      l[hh] = l[hh] * expf(m[hh] - nm) + ol * expf(om - nm);
      m[hh] = nm;
    }
  }

  // per-lane head selection: cols {lane, lane+64} -> heads {lane>>5, (lane>>5)+2}
  bool lo = lane < 32;
  float m0 = lo ? m[0] : m[1];
  float m1 = lo ? m[2] : m[3];
  float il0 = 1.f / (lo ? l[0] : l[1]);
  float il1 = 1.f / (lo ? l[2] : l[3]);
  float ad0 = lo ? adh[0] : adh[1];
  float ad1 = lo ? adh[2] : adh[3];
  int h0 = lane >> 5;
  int h1 = h0 + 2;

  float acc0 = 0.f, acc1 = 0.f;
  int j = start;
  for (; j + 4 <= end; j += 4) {
    int s0 = ssrc[j], s1 = ssrc[j + 1], s2 = ssrc[j + 2], s3 = ssrc[j + 3];
    float g00 = h[(size_t)s0 * 128 + lane], g01 = h[(size_t)s0 * 128 + 64 + lane];
    float g10 = h[(size_t)s1 * 128 + lane], g11 = h[(size_t)s1 * 128 + 64 + lane];
    float g20 = h[(size_t)s2 * 128 + lane], g21 = h[(size_t)s2 * 128 + 64 + lane];
    float g30 = h[(size_t)s3 * 128 + lane], g31 = h[(size_t)s3 * 128 + 64 + lane];
    float p00 = a_s[s0 * 4 + h0], p01 = a_s[s0 * 4 + h1];
    float p10 = a_s[s1 * 4 + h0], p11 = a_s[s1 * 4 + h1];
    float p20 = a_s[s2 * 4 + h0], p21 = a_s[s2 * 4 + h1];
    float p30 = a_s[s3 * 4 + h0], p31 = a_s[s3 * 4 + h1];
    acc0 += expf(lrelu02(p00 + ad0) - m0) * il0 * g00;
    acc1 += expf(lrelu02(p01 + ad1) - m1) * il1 * g01;
    acc0 += expf(lrelu02(p10 + ad0) - m0) * il0 * g10;
    acc1 += expf(lrelu02(p11 + ad1) - m1) * il1 * g11;
    acc0 += expf(lrelu02(p20 + ad0) - m0) * il0 * g20;
    acc1 += expf(lrelu02(p21 + ad1) - m1) * il1 * g21;
    acc0 += expf(lrelu02(p30 + ad0) - m0) * il0 * g30;
    acc1 += expf(lrelu02(p31 + ad1) - m1) * il1 * g31;
  }
  for (; j < end; ++j) {
    int s = ssrc[j];
    float g0 = h[(size_t)s * 128 + lane], g1 = h[(size_t)s * 128 + 64 + lane];
    float p0 = a_s[s * 4 + h0], p1 = a_s[s * 4 + h1];
    acc0 += expf(lrelu02(p0 + ad0) - m0) * il0 * g0;
    acc1 += expf(lrelu02(p1 + ad1) - m1) * il1 * g1;
  }
  out[(size_t)d * 128 + lane] = acc0;
  out[(size_t)d * 128 + 64 + lane] = acc1;
}

// -------------------------- BatchNorm batch stats --------------------------
__global__ __launch_bounds__(256) void bn_stats_k(const float* __restrict__ out,
                                                  float* __restrict__ sums,
                                                  float* __restrict__ sumsq, int n) {
  int j = threadIdx.x & 127;
  int strm = blockIdx.x * 2 + (threadIdx.x >> 7);
  int stride = gridDim.x * 2;
  float s = 0.f, s2 = 0.f;
  for (int r = strm; r < n; r += stride) {
    float v = out[(size_t)r * 128 + j];
    s += v;
    s2 += v * v;
  }
  atomicAdd(&sums[j], s);
  atomicAdd(&sumsq[j], s2);
}

__global__ void bn_coef_k(const float* __restrict__ sums,
                          const float* __restrict__ sumsq,
                          const float* __restrict__ gamma,
                          const float* __restrict__ beta,
                          float* __restrict__ scale, float* __restrict__ shift,
                          float inv_n) {
  int j = threadIdx.x;
  float mu = sums[j] * inv_n;
  float var = sumsq[j] * inv_n - mu * mu;
  float rstd = 1.0f / sqrtf(var + 1e-5f);
  float g = gamma[j] * rstd;
  scale[j] = g;
  shift[j] = beta[j] - mu * g;
}

__global__ __launch_bounds__(256) void bn_apply_k(float* __restrict__ out,
                                                  const float* __restrict__ scale,
                                                  const float* __restrict__ shift,
                                                  int n4) {
  int i = blockIdx.x * 256 + threadIdx.x;
  if (i >= n4) return;
  float4 v = ((float4*)out)[i];
  int j = (i & 31) << 2;
  const float4 sc = *(const float4*)&scale[j];
  const float4 sh = *(const float4*)&shift[j];
  v.x = fmaf(v.x, sc.x, sh.x);
  v.y = fmaf(v.y, sc.y, sh.y);
  v.z = fmaf(v.z, sc.z, sh.z);
  v.w = fmaf(v.w, sc.w, sh.w);
  v.x = v.x > 0.f ? v.x : 0.01f * v.x;
  v.y = v.y > 0.f ? v.y : 0.01f * v.y;
  v.z = v.z > 0.f ? v.z : 0.01f * v.z;
  v.w = v.w > 0.f ? v.w : 0.01f * v.w;
  ((float4*)out)[i] = v;
}

static inline char* align16(char* p) {
  return (char*)(((uintptr_t)p + 15) & ~(uintptr_t)15);
}

extern "C" void kernel_launch(void* const* d_in, const int* in_sizes, int n_in,
                              void* d_out, int out_size, void* d_ws, size_t ws_size,
                              hipStream_t stream) {
  const float* x     = (const float*)d_in[0];
  const int*   ei    = (const int*)d_in[1];
  const float* W     = (const float*)d_in[2];
  const float* att_s = (const float*)d_in[3];
  const float* att_d = (const float*)d_in[4];
  // d_in[5] = bias: cancels under batch-stat BN
  const float* gamma = (const float*)d_in[6];
  const float* beta  = (const float*)d_in[7];

  int n = in_sizes[0] / 256;
  int E = in_sizes[1] / 2;
  int tot = E + n;
  const int* src = ei;
  const int* dstp = ei + E;
  float* out = (float*)d_out;

  int NB = (n + 255) / 256;

  char* p = (char*)d_ws;
  float* h     = (float*)p; p = align16(p + (size_t)n * 128 * 4);
  float* a_s   = (float*)p; p = align16(p + (size_t)n * 4 * 4);
  float* a_d   = (float*)p; p = align16(p + (size_t)n * 4 * 4);
  float* sums  = (float*)p; p = align16(p + 128 * 4);
  float* sumsq = (float*)p; p = align16(p + 128 * 4);
  float* scale = (float*)p; p = align16(p + 128 * 4);
  float* shift = (float*)p; p = align16(p + 128 * 4);
  int* deg     = (int*)p;   p = align16(p + (size_t)n * 4);
  int* off     = (int*)p;   p = align16(p + (size_t)(n + 1) * 4);
  int* cur     = (int*)p;   p = align16(p + (size_t)n * 4);
  int* bsum    = (int*)p;   p = align16(p + (size_t)NB * 4);
  int* ssrc    = (int*)p;   p = align16(p + (size_t)tot * 4);

  hipMemsetAsync(sums, 0, 2 * 128 * 4, stream);  // sums+sumsq contiguous

  gemm_xwt<<<(n + 63) / 64, 256, 0, stream>>>(x, W, h, n);
  att_scores<<<(n + 3) / 4, 256, 0, stream>>>(h, att_s, att_d, a_s, a_d, n);

  deg_init_k<<<NB, 256, 0, stream>>>(deg, n);
  deg_count_k<<<(E + 255) / 256, 256, 0, stream>>>(dstp, deg, E);
  blocksum_k<<<NB, 256, 0, stream>>>(deg, bsum, n);
  scan_bsum_k<<<1, 1024, 0, stream>>>(bsum, NB);
  offsets_k<<<NB, 256, 0, stream>>>(deg, bsum, off, cur, n, tot);
  scatter_k<<<(tot + 255) / 256, 256, 0, stream>>>(src, dstp, cur, ssrc, E, n);

  agg_csr_k<<<(n + 3) / 4, 256, 0, stream>>>(off, ssrc, a_s, a_d, h, out, n);

  bn_stats_k<<<256, 256, 0, stream>>>(out, sums, sumsq, n);
  bn_coef_k<<<1, 128, 0, stream>>>(sums, sumsq, gamma, beta, scale, shift, 1.0f / n);
  bn_apply_k<<<(n * 32 + 255) / 256, 256, 0, stream>>>(out, scale, shift, n * 32);
}

// Round 3
// 388.213 us; speedup vs baseline: 2.2551x; 1.1723x over previous
//
#include <hip/hip_runtime.h>
#include <hip/hip_bf16.h>
#include <math.h>

// F_IN=256, H=4, C=32, H*C=128; NEG_SLOPE_ATT=0.2, NEG_SLOPE_ACT=0.01, EPS=1e-5
// bias skipped: batch-stat BatchNorm subtracts it exactly.
//
// R1: CSR-by-dst + one-wave-per-node aggregation (no output atomics).
// R2: agg_csr_k de-redundified: 4 exp per EDGE (was 128), unnormalized-p
//     accumulation with end normalization (kills the separate sum pass),
//     LDS-staged (src, p) chunks, scalar-base gathers, 2x unroll.

__device__ inline float lrelu02(float v) { return v > 0.f ? v : 0.2f * v; }

// ---------------- GEMM: h[n][128] = x[n][256] @ W[128][256]^T ----------------
__global__ __launch_bounds__(256) void gemm_xwt(const float* __restrict__ x,
                                                const float* __restrict__ w,
                                                float* __restrict__ hout, int n) {
  __shared__ float xs[32][64];    // [k][row]
  __shared__ float wsl[32][128];  // [k][col]
  int tid = threadIdx.x;
  int row0 = blockIdx.x * 64;
  int rg = tid >> 5;
  int cg = tid & 31;
  float acc[8][4];
#pragma unroll
  for (int i = 0; i < 8; i++)
#pragma unroll
    for (int j = 0; j < 4; j++) acc[i][j] = 0.f;

  for (int kk = 0; kk < 256; kk += 32) {
    __syncthreads();
#pragma unroll
    for (int i = 0; i < 2; i++) {
      int f4 = tid + i * 256;
      int r = f4 >> 3;
      int k4 = f4 & 7;
      int grow = row0 + r;
      float4 v = make_float4(0.f, 0.f, 0.f, 0.f);
      if (grow < n) v = *(const float4*)&x[(size_t)grow * 256 + kk + k4 * 4];
      xs[k4 * 4 + 0][r] = v.x;
      xs[k4 * 4 + 1][r] = v.y;
      xs[k4 * 4 + 2][r] = v.z;
      xs[k4 * 4 + 3][r] = v.w;
    }
#pragma unroll
    for (int i = 0; i < 4; i++) {
      int f4 = tid + i * 256;
      int c = f4 >> 3;
      int k4 = f4 & 7;
      float4 v = *(const float4*)&w[(size_t)c * 256 + kk + k4 * 4];
      wsl[k4 * 4 + 0][c] = v.x;
      wsl[k4 * 4 + 1][c] = v.y;
      wsl[k4 * 4 + 2][c] = v.z;
      wsl[k4 * 4 + 3][c] = v.w;
    }
    __syncthreads();
#pragma unroll
    for (int k = 0; k < 32; ++k) {
      float4 a0 = *(const float4*)&xs[k][rg * 8];
      float4 a1 = *(const float4*)&xs[k][rg * 8 + 4];
      float4 bv = *(const float4*)&wsl[k][cg * 4];
      float av[8] = {a0.x, a0.y, a0.z, a0.w, a1.x, a1.y, a1.z, a1.w};
      float bb[4] = {bv.x, bv.y, bv.z, bv.w};
#pragma unroll
      for (int i = 0; i < 8; i++)
#pragma unroll
        for (int j = 0; j < 4; j++) acc[i][j] = fmaf(av[i], bb[j], acc[i][j]);
    }
  }
#pragma unroll
  for (int i = 0; i < 8; i++) {
    int grow = row0 + rg * 8 + i;
    if (grow < n)
      *(float4*)&hout[(size_t)grow * 128 + cg * 4] =
          make_float4(acc[i][0], acc[i][1], acc[i][2], acc[i][3]);
  }
}

// ------------- per-node attention scores: a_s[n][4], a_d[n][4] -------------
__global__ __launch_bounds__(256) void att_scores(const float* __restrict__ h,
                                                  const float* __restrict__ att_s,
                                                  const float* __restrict__ att_d,
                                                  float* __restrict__ a_s,
                                                  float* __restrict__ a_d, int n) {
  int wave = (blockIdx.x * 256 + threadIdx.x) >> 6;
  int lane = threadIdx.x & 63;
  if (wave >= n) return;
  float h0 = h[(size_t)wave * 128 + lane];
  float h1 = h[(size_t)wave * 128 + 64 + lane];
  float s0 = h0 * att_s[lane], s1 = h1 * att_s[64 + lane];
  float d0 = h0 * att_d[lane], d1 = h1 * att_d[64 + lane];
#pragma unroll
  for (int off = 16; off; off >>= 1) {
    s0 += __shfl_down(s0, off, 32);
    s1 += __shfl_down(s1, off, 32);
    d0 += __shfl_down(d0, off, 32);
    d1 += __shfl_down(d1, off, 32);
  }
  if ((lane & 31) == 0) {
    int half = lane >> 5;
    a_s[wave * 4 + half] = s0;
    a_s[wave * 4 + 2 + half] = s1;
    a_d[wave * 4 + half] = d0;
    a_d[wave * 4 + 2 + half] = d1;
  }
}

// ------------------------------ CSR build ------------------------------
// deg[] memset to 0 host-side; self-loop folded in as +1 at scan time.
__global__ __launch_bounds__(256) void deg_count_k(const int* __restrict__ dst,
                                                   int* __restrict__ deg, int E) {
  int i = blockIdx.x * 256 + threadIdx.x;
  if (i < E) atomicAdd(&deg[dst[i]], 1);
}

__global__ __launch_bounds__(256) void blocksum_k(const int* __restrict__ deg,
                                                  int* __restrict__ bsum, int n) {
  __shared__ int sd[256];
  int i = blockIdx.x * 256 + threadIdx.x;
  sd[threadIdx.x] = (i < n) ? (deg[i] + 1) : 0;
  __syncthreads();
  for (int o = 128; o; o >>= 1) {
    if (threadIdx.x < o) sd[threadIdx.x] += sd[threadIdx.x + o];
    __syncthreads();
  }
  if (threadIdx.x == 0) bsum[blockIdx.x] = sd[0];
}

__global__ __launch_bounds__(1024) void scan_bsum_k(int* __restrict__ bsum, int nb) {
  __shared__ int sd[1024];
  int t = threadIdx.x;
  int v = (t < nb) ? bsum[t] : 0;
  sd[t] = v;
  __syncthreads();
  for (int o = 1; o < 1024; o <<= 1) {
    int x = (t >= o) ? sd[t - o] : 0;
    __syncthreads();
    sd[t] += x;
    __syncthreads();
  }
  if (t < nb) bsum[t] = sd[t] - v;  // exclusive
}

__global__ __launch_bounds__(256) void offsets_k(const int* __restrict__ deg,
                                                 const int* __restrict__ bsum,
                                                 int* __restrict__ off,
                                                 int* __restrict__ cur,
                                                 int n, int total) {
  __shared__ int sd[256];
  int t = threadIdx.x;
  int i = blockIdx.x * 256 + t;
  int v = (i < n) ? (deg[i] + 1) : 0;
  sd[t] = v;
  __syncthreads();
  for (int o = 1; o < 256; o <<= 1) {
    int x = (t >= o) ? sd[t - o] : 0;
    __syncthreads();
    sd[t] += x;
    __syncthreads();
  }
  if (i < n) {
    int ov = bsum[blockIdx.x] + sd[t] - v;
    off[i] = ov;
    cur[i] = ov;
    if (i == n - 1) off[n] = total;
  }
}

__global__ __launch_bounds__(256) void scatter_k(const int* __restrict__ src,
                                                 const int* __restrict__ dst,
                                                 int* __restrict__ cur,
                                                 int* __restrict__ ssrc, int E, int n) {
  int i = blockIdx.x * 256 + threadIdx.x;
  if (i >= E + n) return;
  int s, d;
  if (i < E) { s = src[i]; d = dst[i]; } else { s = d = i - E; }
  int pos = atomicAdd(&cur[d], 1);
  ssrc[pos] = s;
}

// -------- fused softmax-max + weighted aggregation, one wave per dst --------
// Unnormalized accumulation: out = (sum_e p_e * h[src_e]) / l, p_e = exp(e-m).
__global__ __launch_bounds__(256) void agg_csr_k(const int* __restrict__ off,
                                                 const int* __restrict__ ssrc,
                                                 const float* __restrict__ a_s,
                                                 const float* __restrict__ a_d,
                                                 const float* __restrict__ h,
                                                 float* __restrict__ out, int n) {
  __shared__ float lp[4][64 * 4];  // per wave: 64 edges x (p0,p2,p1,p3)
  __shared__ int lsrc[4][64];
  int tid = threadIdx.x;
  int wid = tid >> 6;
  int lane = tid & 63;
  int d = blockIdx.x * 4 + wid;
  if (d >= n) return;  // no block-wide barriers below: safe
  int start = off[d];
  int end = off[d + 1];
  float4 ad4 = *(const float4*)&a_d[d * 4];

  // ---- pass 1: per-head max over incoming edges (no exp) ----
  float mx0 = -1e30f, mx1 = -1e30f, mx2 = -1e30f, mx3 = -1e30f;
  for (int j = start + lane; j < end; j += 64) {
    int s = ssrc[j];
    float4 as4 = *(const float4*)&a_s[s * 4];
    mx0 = fmaxf(mx0, lrelu02(as4.x + ad4.x));
    mx1 = fmaxf(mx1, lrelu02(as4.y + ad4.y));
    mx2 = fmaxf(mx2, lrelu02(as4.z + ad4.z));
    mx3 = fmaxf(mx3, lrelu02(as4.w + ad4.w));
  }
#pragma unroll
  for (int o = 1; o < 64; o <<= 1) {
    mx0 = fmaxf(mx0, __shfl_xor(mx0, o, 64));
    mx1 = fmaxf(mx1, __shfl_xor(mx1, o, 64));
    mx2 = fmaxf(mx2, __shfl_xor(mx2, o, 64));
    mx3 = fmaxf(mx3, __shfl_xor(mx3, o, 64));
  }

  // ---- pass 2: chunk 64 edges; 1 lane = 1 edge's weights; all lanes gather ----
  int half = lane >> 5;
  float l0 = 0.f, l1 = 0.f, l2 = 0.f, l3 = 0.f;
  float acc0 = 0.f, acc1 = 0.f;
  for (int base = start; base < end; base += 64) {
    int cnt = min(64, end - base);
    int j = base + lane;
    if (j < end) {
      int s = ssrc[j];
      float4 as4 = *(const float4*)&a_s[s * 4];
      float p0 = __expf(lrelu02(as4.x + ad4.x) - mx0);
      float p1 = __expf(lrelu02(as4.y + ad4.y) - mx1);
      float p2 = __expf(lrelu02(as4.z + ad4.z) - mx2);
      float p3 = __expf(lrelu02(as4.w + ad4.w) - mx3);
      l0 += p0; l1 += p1; l2 += p2; l3 += p3;
      lsrc[wid][lane] = s;
      *(float4*)&lp[wid][lane * 4] = make_float4(p0, p2, p1, p3);
    }
    // same-wave LDS write->read: DS pipe in-order per wave; alias dep keeps order
    int k = 0;
    for (; k + 2 <= cnt; k += 2) {
      int sA = __builtin_amdgcn_readfirstlane(lsrc[wid][k]);
      int sB = __builtin_amdgcn_readfirstlane(lsrc[wid][k + 1]);
      float2 pA = *(const float2*)&lp[wid][k * 4 + half * 2];
      float2 pB = *(const float2*)&lp[wid][(k + 1) * 4 + half * 2];
      const float* hA = h + (size_t)sA * 128;
      const float* hB = h + (size_t)sB * 128;
      float gA0 = hA[lane], gA1 = hA[64 + lane];
      float gB0 = hB[lane], gB1 = hB[64 + lane];
      acc0 = fmaf(pA.x, gA0, acc0);
      acc1 = fmaf(pA.y, gA1, acc1);
      acc0 = fmaf(pB.x, gB0, acc0);
      acc1 = fmaf(pB.y, gB1, acc1);
    }
    if (k < cnt) {
      int sA = __builtin_amdgcn_readfirstlane(lsrc[wid][k]);
      float2 pA = *(const float2*)&lp[wid][k * 4 + half * 2];
      const float* hA = h + (size_t)sA * 128;
      acc0 = fmaf(pA.x, hA[lane], acc0);
      acc1 = fmaf(pA.y, hA[64 + lane], acc1);
    }
  }

  // ---- denominators: butterfly-sum l, normalize, store ----
#pragma unroll
  for (int o = 1; o < 64; o <<= 1) {
    l0 += __shfl_xor(l0, o, 64);
    l1 += __shfl_xor(l1, o, 64);
    l2 += __shfl_xor(l2, o, 64);
    l3 += __shfl_xor(l3, o, 64);
  }
  float ilo = 1.0f / (half ? l1 : l0);
  float ihi = 1.0f / (half ? l3 : l2);
  out[(size_t)d * 128 + lane] = acc0 * ilo;
  out[(size_t)d * 128 + 64 + lane] = acc1 * ihi;
}

// -------------------------- BatchNorm batch stats --------------------------
__global__ __launch_bounds__(256) void bn_stats_k(const float* __restrict__ out,
                                                  float* __restrict__ sums,
                                                  float* __restrict__ sumsq, int n) {
  int j = threadIdx.x & 127;
  int strm = blockIdx.x * 2 + (threadIdx.x >> 7);
  int stride = gridDim.x * 2;
  float s = 0.f, s2 = 0.f;
  for (int r = strm; r < n; r += stride) {
    float v = out[(size_t)r * 128 + j];
    s += v;
    s2 += v * v;
  }
  atomicAdd(&sums[j], s);
  atomicAdd(&sumsq[j], s2);
}

__global__ void bn_coef_k(const float* __restrict__ sums,
                          const float* __restrict__ sumsq,
                          const float* __restrict__ gamma,
                          const float* __restrict__ beta,
                          float* __restrict__ scale, float* __restrict__ shift,
                          float inv_n) {
  int j = threadIdx.x;
  float mu = sums[j] * inv_n;
  float var = sumsq[j] * inv_n - mu * mu;
  float rstd = 1.0f / sqrtf(var + 1e-5f);
  float g = gamma[j] * rstd;
  scale[j] = g;
  shift[j] = beta[j] - mu * g;
}

__global__ __launch_bounds__(256) void bn_apply_k(float* __restrict__ out,
                                                  const float* __restrict__ scale,
                                                  const float* __restrict__ shift,
                                                  int n4) {
  int i = blockIdx.x * 256 + threadIdx.x;
  if (i >= n4) return;
  float4 v = ((float4*)out)[i];
  int j = (i & 31) << 2;
  const float4 sc = *(const float4*)&scale[j];
  const float4 sh = *(const float4*)&shift[j];
  v.x = fmaf(v.x, sc.x, sh.x);
  v.y = fmaf(v.y, sc.y, sh.y);
  v.z = fmaf(v.z, sc.z, sh.z);
  v.w = fmaf(v.w, sc.w, sh.w);
  v.x = v.x > 0.f ? v.x : 0.01f * v.x;
  v.y = v.y > 0.f ? v.y : 0.01f * v.y;
  v.z = v.z > 0.f ? v.z : 0.01f * v.z;
  v.w = v.w > 0.f ? v.w : 0.01f * v.w;
  ((float4*)out)[i] = v;
}

static inline char* align16(char* p) {
  return (char*)(((uintptr_t)p + 15) & ~(uintptr_t)15);
}

extern "C" void kernel_launch(void* const* d_in, const int* in_sizes, int n_in,
                              void* d_out, int out_size, void* d_ws, size_t ws_size,
                              hipStream_t stream) {
  const float* x     = (const float*)d_in[0];
  const int*   ei    = (const int*)d_in[1];
  const float* W     = (const float*)d_in[2];
  const float* att_s = (const float*)d_in[3];
  const float* att_d = (const float*)d_in[4];
  // d_in[5] = bias: cancels under batch-stat BN
  const float* gamma = (const float*)d_in[6];
  const float* beta  = (const float*)d_in[7];

  int n = in_sizes[0] / 256;
  int E = in_sizes[1] / 2;
  int tot = E + n;
  const int* src = ei;
  const int* dstp = ei + E;
  float* out = (float*)d_out;

  int NB = (n + 255) / 256;

  char* p = (char*)d_ws;
  float* h     = (float*)p; p = align16(p + (size_t)n * 128 * 4);
  float* a_s   = (float*)p; p = align16(p + (size_t)n * 4 * 4);
  float* a_d   = (float*)p; p = align16(p + (size_t)n * 4 * 4);
  float* sums  = (float*)p; p = align16(p + 128 * 4);
  float* sumsq = (float*)p; p = align16(p + 128 * 4);
  float* scale = (float*)p; p = align16(p + 128 * 4);
  float* shift = (float*)p; p = align16(p + 128 * 4);
  int* deg     = (int*)p;   p = align16(p + (size_t)n * 4);
  int* off     = (int*)p;   p = align16(p + (size_t)(n + 1) * 4);
  int* cur     = (int*)p;   p = align16(p + (size_t)n * 4);
  int* bsum    = (int*)p;   p = align16(p + (size_t)NB * 4);
  int* ssrc    = (int*)p;   p = align16(p + (size_t)tot * 4);

  hipMemsetAsync(sums, 0, 2 * 128 * 4, stream);  // sums+sumsq contiguous
  hipMemsetAsync(deg, 0, (size_t)n * 4, stream);

  gemm_xwt<<<(n + 63) / 64, 256, 0, stream>>>(x, W, h, n);
  att_scores<<<(n + 3) / 4, 256, 0, stream>>>(h, att_s, att_d, a_s, a_d, n);

  deg_count_k<<<(E + 255) / 256, 256, 0, stream>>>(dstp, deg, E);
  blocksum_k<<<NB, 256, 0, stream>>>(deg, bsum, n);
  scan_bsum_k<<<1, 1024, 0, stream>>>(bsum, NB);
  offsets_k<<<NB, 256, 0, stream>>>(deg, bsum, off, cur, n, tot);
  scatter_k<<<(tot + 255) / 256, 256, 0, stream>>>(src, dstp, cur, ssrc, E, n);

  agg_csr_k<<<(n + 3) / 4, 256, 0, stream>>>(off, ssrc, a_s, a_d, h, out, n);

  bn_stats_k<<<256, 256, 0, stream>>>(out, sums, sumsq, n);
  bn_coef_k<<<1, 128, 0, stream>>>(sums, sumsq, gamma, beta, scale, shift, 1.0f / n);
  bn_apply_k<<<(n * 32 + 255) / 256, 256, 0, stream>>>(out, scale, shift, n * 32);
}

// Round 5
// 329.336 us; speedup vs baseline: 2.6583x; 1.1788x over previous
//
#include <hip/hip_runtime.h>
#include <hip/hip_bf16.h>
#include <math.h>

// F_IN=256, H=4, C=32, H*C=128; NEG_SLOPE_ATT=0.2, NEG_SLOPE_ACT=0.01, EPS=1e-5
// bias skipped: batch-stat BatchNorm subtracts it exactly.
//
// R1: CSR-by-dst + one-wave-per-node aggregation (no output atomics).
// R2: agg de-redundified (4 exp/edge), unnormalized-p + end normalization.
// R3: GEMM -> bf16 MFMA; h stored bf16.
// R4: FIX R3 staging bug: x tile is 64 rows = 16 float4/thread (was 4 ->
//     rows 16..63 of xsl uninitialized -> NaN). pre[16] register prefetch.

typedef __attribute__((ext_vector_type(8))) short bf8_t;   // 8 bf16 in 4 VGPRs
typedef __attribute__((ext_vector_type(4))) float f4_t;    // MFMA accumulator

__device__ inline unsigned short f2bf(float f) {  // RNE fp32->bf16
  unsigned u = __float_as_uint(f);
  u += 0x7fff + ((u >> 16) & 1);
  return (unsigned short)(u >> 16);
}
__device__ inline float bf2f(unsigned short s) {
  return __uint_as_float(((unsigned)s) << 16);
}
__device__ inline float lrelu02(float v) { return v > 0.f ? v : 0.2f * v; }

#define LSTRIDE 264  // 256 + 8 bf16 pad: 16B-aligned rows, stagger banks

// ------- MFMA GEMM: h[n][128](bf16) = x[n][256](f32) @ W[128][256]^T -------
__global__ __launch_bounds__(256) void gemm_mfma(const float* __restrict__ x,
                                                 const float* __restrict__ w,
                                                 unsigned short* __restrict__ hb,
                                                 int n, int ntiles) {
  __shared__ unsigned short wsl[128 * LSTRIDE];  // 67.6 KB
  __shared__ unsigned short xsl[64 * LSTRIDE];   // 33.8 KB
  int tid = threadIdx.x;
  int lane = tid & 63;
  int wid = tid >> 6;
  int quad = lane >> 4;
  int l15 = lane & 15;

  // stage W once: 128 rows x 64 float4 = 8192 f4, 32/thread
#pragma unroll 4
  for (int i = 0; i < 32; i++) {
    int idx = tid + i * 256;
    int row = idx >> 6;
    int f4 = idx & 63;
    float4 v = *(const float4*)&w[(size_t)row * 256 + f4 * 4];
    unsigned p01 = f2bf(v.x) | ((unsigned)f2bf(v.y) << 16);
    unsigned p23 = f2bf(v.z) | ((unsigned)f2bf(v.w) << 16);
    *(uint2*)&wsl[row * LSTRIDE + f4 * 4] = make_uint2(p01, p23);
  }

  // x tile: 64 rows x 64 float4 = 4096 f4, 16/thread
  float4 pre[16];
  int tile = blockIdx.x;
  if (tile < ntiles) {
#pragma unroll
    for (int i = 0; i < 16; i++) {
      int idx = tid + i * 256;
      int row = idx >> 6, f4 = idx & 63;
      int grow = tile * 64 + row;
      pre[i] = (grow < n) ? *(const float4*)&x[(size_t)grow * 256 + f4 * 4]
                          : make_float4(0.f, 0.f, 0.f, 0.f);
    }
  }

  for (; tile < ntiles; tile += gridDim.x) {
    __syncthreads();  // previous compute done (also covers W staging, iter 0)
#pragma unroll
    for (int i = 0; i < 16; i++) {
      int idx = tid + i * 256;
      int row = idx >> 6, f4 = idx & 63;
      unsigned p01 = f2bf(pre[i].x) | ((unsigned)f2bf(pre[i].y) << 16);
      unsigned p23 = f2bf(pre[i].z) | ((unsigned)f2bf(pre[i].w) << 16);
      *(uint2*)&xsl[row * LSTRIDE + f4 * 4] = make_uint2(p01, p23);
    }
    __syncthreads();

    int nxt = tile + gridDim.x;
    if (nxt < ntiles) {  // prefetch next tile; overlaps MFMA below
#pragma unroll
      for (int i = 0; i < 16; i++) {
        int idx = tid + i * 256;
        int row = idx >> 6, f4 = idx & 63;
        int grow = nxt * 64 + row;
        pre[i] = (grow < n) ? *(const float4*)&x[(size_t)grow * 256 + f4 * 4]
                            : make_float4(0.f, 0.f, 0.f, 0.f);
      }
    }

    f4_t acc[8];
#pragma unroll
    for (int t = 0; t < 8; t++) acc[t] = (f4_t){0.f, 0.f, 0.f, 0.f};
    const unsigned short* arow = &xsl[(wid * 16 + l15) * LSTRIDE];
#pragma unroll
    for (int ks = 0; ks < 8; ks++) {
      bf8_t af = *(const bf8_t*)&arow[ks * 32 + quad * 8];
#pragma unroll
      for (int t = 0; t < 8; t++) {
        bf8_t bf = *(const bf8_t*)&wsl[(t * 16 + l15) * LSTRIDE + ks * 32 + quad * 8];
        acc[t] = __builtin_amdgcn_mfma_f32_16x16x32_bf16(af, bf, acc[t], 0, 0, 0);
      }
    }

    // C/D layout: col = lane&15, row = quad*4 + reg  [m89-verified]
    int growb = tile * 64 + wid * 16 + quad * 4;
#pragma unroll
    for (int r = 0; r < 4; r++) {
      int grow = growb + r;
      if (grow < n) {
        unsigned short* orow = &hb[(size_t)grow * 128 + l15];
#pragma unroll
        for (int t = 0; t < 8; t++) orow[t * 16] = f2bf(acc[t][r]);
      }
    }
  }
}

// ------------- per-node attention scores from bf16 h -------------
__global__ __launch_bounds__(256) void att_scores(const unsigned short* __restrict__ hb,
                                                  const float* __restrict__ att_s,
                                                  const float* __restrict__ att_d,
                                                  float* __restrict__ a_s,
                                                  float* __restrict__ a_d, int n) {
  int wave = (blockIdx.x * 256 + threadIdx.x) >> 6;
  int lane = threadIdx.x & 63;
  if (wave >= n) return;
  float h0 = bf2f(hb[(size_t)wave * 128 + lane]);
  float h1 = bf2f(hb[(size_t)wave * 128 + 64 + lane]);
  float s0 = h0 * att_s[lane], s1 = h1 * att_s[64 + lane];
  float d0 = h0 * att_d[lane], d1 = h1 * att_d[64 + lane];
#pragma unroll
  for (int off = 16; off; off >>= 1) {
    s0 += __shfl_down(s0, off, 32);
    s1 += __shfl_down(s1, off, 32);
    d0 += __shfl_down(d0, off, 32);
    d1 += __shfl_down(d1, off, 32);
  }
  if ((lane & 31) == 0) {
    int half = lane >> 5;
    a_s[wave * 4 + half] = s0;
    a_s[wave * 4 + 2 + half] = s1;
    a_d[wave * 4 + half] = d0;
    a_d[wave * 4 + 2 + half] = d1;
  }
}

// ------------------------------ CSR build ------------------------------
__global__ __launch_bounds__(256) void deg_count_k(const int* __restrict__ dst,
                                                   int* __restrict__ deg, int E) {
  int i = blockIdx.x * 256 + threadIdx.x;
  if (i < E) atomicAdd(&deg[dst[i]], 1);
}

__global__ __launch_bounds__(256) void blocksum_k(const int* __restrict__ deg,
                                                  int* __restrict__ bsum, int n) {
  __shared__ int sd[256];
  int i = blockIdx.x * 256 + threadIdx.x;
  sd[threadIdx.x] = (i < n) ? (deg[i] + 1) : 0;
  __syncthreads();
  for (int o = 128; o; o >>= 1) {
    if (threadIdx.x < o) sd[threadIdx.x] += sd[threadIdx.x + o];
    __syncthreads();
  }
  if (threadIdx.x == 0) bsum[blockIdx.x] = sd[0];
}

__global__ __launch_bounds__(1024) void scan_bsum_k(int* __restrict__ bsum, int nb) {
  __shared__ int sd[1024];
  int t = threadIdx.x;
  int v = (t < nb) ? bsum[t] : 0;
  sd[t] = v;
  __syncthreads();
  for (int o = 1; o < 1024; o <<= 1) {
    int x = (t >= o) ? sd[t - o] : 0;
    __syncthreads();
    sd[t] += x;
    __syncthreads();
  }
  if (t < nb) bsum[t] = sd[t] - v;  // exclusive
}

__global__ __launch_bounds__(256) void offsets_k(const int* __restrict__ deg,
                                                 const int* __restrict__ bsum,
                                                 int* __restrict__ off,
                                                 int* __restrict__ cur,
                                                 int n, int total) {
  __shared__ int sd[256];
  int t = threadIdx.x;
  int i = blockIdx.x * 256 + t;
  int v = (i < n) ? (deg[i] + 1) : 0;
  sd[t] = v;
  __syncthreads();
  for (int o = 1; o < 256; o <<= 1) {
    int x = (t >= o) ? sd[t - o] : 0;
    __syncthreads();
    sd[t] += x;
    __syncthreads();
  }
  if (i < n) {
    int ov = bsum[blockIdx.x] + sd[t] - v;
    off[i] = ov;
    cur[i] = ov;
    if (i == n - 1) off[n] = total;
  }
}

__global__ __launch_bounds__(256) void scatter_k(const int* __restrict__ src,
                                                 const int* __restrict__ dst,
                                                 int* __restrict__ cur,
                                                 int* __restrict__ ssrc, int E, int n) {
  int i = blockIdx.x * 256 + threadIdx.x;
  if (i >= E + n) return;
  int s, d;
  if (i < E) { s = src[i]; d = dst[i]; } else { s = d = i - E; }
  int pos = atomicAdd(&cur[d], 1);
  ssrc[pos] = s;
}

// -------- fused softmax-max + weighted aggregation, one wave per dst --------
__global__ __launch_bounds__(256) void agg_csr_k(const int* __restrict__ off,
                                                 const int* __restrict__ ssrc,
                                                 const float* __restrict__ a_s,
                                                 const float* __restrict__ a_d,
                                                 const unsigned short* __restrict__ hb,
                                                 float* __restrict__ out, int n) {
  __shared__ float lp[4][64 * 4];
  __shared__ int lsrc[4][64];
  int tid = threadIdx.x;
  int wid = tid >> 6;
  int lane = tid & 63;
  int d = blockIdx.x * 4 + wid;
  if (d >= n) return;  // no block-wide barriers below: safe
  int start = off[d];
  int end = off[d + 1];
  float4 ad4 = *(const float4*)&a_d[d * 4];

  // pass 1: per-head max (no exp)
  float mx0 = -1e30f, mx1 = -1e30f, mx2 = -1e30f, mx3 = -1e30f;
  for (int j = start + lane; j < end; j += 64) {
    int s = ssrc[j];
    float4 as4 = *(const float4*)&a_s[s * 4];
    mx0 = fmaxf(mx0, lrelu02(as4.x + ad4.x));
    mx1 = fmaxf(mx1, lrelu02(as4.y + ad4.y));
    mx2 = fmaxf(mx2, lrelu02(as4.z + ad4.z));
    mx3 = fmaxf(mx3, lrelu02(as4.w + ad4.w));
  }
#pragma unroll
  for (int o = 1; o < 64; o <<= 1) {
    mx0 = fmaxf(mx0, __shfl_xor(mx0, o, 64));
    mx1 = fmaxf(mx1, __shfl_xor(mx1, o, 64));
    mx2 = fmaxf(mx2, __shfl_xor(mx2, o, 64));
    mx3 = fmaxf(mx3, __shfl_xor(mx3, o, 64));
  }

  // pass 2: 64-edge chunks; 1 lane computes 1 edge's 4 weights; all lanes gather
  int half = lane >> 5;
  float l0 = 0.f, l1 = 0.f, l2 = 0.f, l3 = 0.f;
  float acc0 = 0.f, acc1 = 0.f;
  for (int base = start; base < end; base += 64) {
    int cnt = min(64, end - base);
    int j = base + lane;
    if (j < end) {
      int s = ssrc[j];
      float4 as4 = *(const float4*)&a_s[s * 4];
      float p0 = __expf(lrelu02(as4.x + ad4.x) - mx0);
      float p1 = __expf(lrelu02(as4.y + ad4.y) - mx1);
      float p2 = __expf(lrelu02(as4.z + ad4.z) - mx2);
      float p3 = __expf(lrelu02(as4.w + ad4.w) - mx3);
      l0 += p0; l1 += p1; l2 += p2; l3 += p3;
      lsrc[wid][lane] = s;
      *(float4*)&lp[wid][lane * 4] = make_float4(p0, p2, p1, p3);
    }
    int k = 0;
    for (; k + 2 <= cnt; k += 2) {
      int sA = __builtin_amdgcn_readfirstlane(lsrc[wid][k]);
      int sB = __builtin_amdgcn_readfirstlane(lsrc[wid][k + 1]);
      float2 pA = *(const float2*)&lp[wid][k * 4 + half * 2];
      float2 pB = *(const float2*)&lp[wid][(k + 1) * 4 + half * 2];
      const unsigned short* hA = hb + (size_t)sA * 128;
      const unsigned short* hB = hb + (size_t)sB * 128;
      float gA0 = bf2f(hA[lane]), gA1 = bf2f(hA[64 + lane]);
      float gB0 = bf2f(hB[lane]), gB1 = bf2f(hB[64 + lane]);
      acc0 = fmaf(pA.x, gA0, acc0);
      acc1 = fmaf(pA.y, gA1, acc1);
      acc0 = fmaf(pB.x, gB0, acc0);
      acc1 = fmaf(pB.y, gB1, acc1);
    }
    if (k < cnt) {
      int sA = __builtin_amdgcn_readfirstlane(lsrc[wid][k]);
      float2 pA = *(const float2*)&lp[wid][k * 4 + half * 2];
      const unsigned short* hA = hb + (size_t)sA * 128;
      acc0 = fmaf(pA.x, bf2f(hA[lane]), acc0);
      acc1 = fmaf(pA.y, bf2f(hA[64 + lane]), acc1);
    }
  }

#pragma unroll
  for (int o = 1; o < 64; o <<= 1) {
    l0 += __shfl_xor(l0, o, 64);
    l1 += __shfl_xor(l1, o, 64);
    l2 += __shfl_xor(l2, o, 64);
    l3 += __shfl_xor(l3, o, 64);
  }
  float ilo = 1.0f / (half ? l1 : l0);
  float ihi = 1.0f / (half ? l3 : l2);
  out[(size_t)d * 128 + lane] = acc0 * ilo;
  out[(size_t)d * 128 + 64 + lane] = acc1 * ihi;
}

// -------------------------- BatchNorm --------------------------
__global__ __launch_bounds__(256) void bn_stats_k(const float* __restrict__ out,
                                                  float* __restrict__ sums,
                                                  float* __restrict__ sumsq, int n) {
  int j = threadIdx.x & 127;
  int strm = blockIdx.x * 2 + (threadIdx.x >> 7);
  int stride = gridDim.x * 2;
  float s = 0.f, s2 = 0.f;
  for (int r = strm; r < n; r += stride) {
    float v = out[(size_t)r * 128 + j];
    s += v;
    s2 += v * v;
  }
  atomicAdd(&sums[j], s);
  atomicAdd(&sumsq[j], s2);
}

__global__ void bn_coef_k(const float* __restrict__ sums,
                          const float* __restrict__ sumsq,
                          const float* __restrict__ gamma,
                          const float* __restrict__ beta,
                          float* __restrict__ scale, float* __restrict__ shift,
                          float inv_n) {
  int j = threadIdx.x;
  float mu = sums[j] * inv_n;
  float var = sumsq[j] * inv_n - mu * mu;
  float rstd = 1.0f / sqrtf(var + 1e-5f);
  float g = gamma[j] * rstd;
  scale[j] = g;
  shift[j] = beta[j] - mu * g;
}

__global__ __launch_bounds__(256) void bn_apply_k(float* __restrict__ out,
                                                  const float* __restrict__ scale,
                                                  const float* __restrict__ shift,
                                                  int n4) {
  int i = blockIdx.x * 256 + threadIdx.x;
  if (i >= n4) return;
  float4 v = ((float4*)out)[i];
  int j = (i & 31) << 2;
  const float4 sc = *(const float4*)&scale[j];
  const float4 sh = *(const float4*)&shift[j];
  v.x = fmaf(v.x, sc.x, sh.x);
  v.y = fmaf(v.y, sc.y, sh.y);
  v.z = fmaf(v.z, sc.z, sh.z);
  v.w = fmaf(v.w, sc.w, sh.w);
  v.x = v.x > 0.f ? v.x : 0.01f * v.x;
  v.y = v.y > 0.f ? v.y : 0.01f * v.y;
  v.z = v.z > 0.f ? v.z : 0.01f * v.z;
  v.w = v.w > 0.f ? v.w : 0.01f * v.w;
  ((float4*)out)[i] = v;
}

static inline char* align16(char* p) {
  return (char*)(((uintptr_t)p + 15) & ~(uintptr_t)15);
}

extern "C" void kernel_launch(void* const* d_in, const int* in_sizes, int n_in,
                              void* d_out, int out_size, void* d_ws, size_t ws_size,
                              hipStream_t stream) {
  const float* x     = (const float*)d_in[0];
  const int*   ei    = (const int*)d_in[1];
  const float* W     = (const float*)d_in[2];
  const float* att_s = (const float*)d_in[3];
  const float* att_d = (const float*)d_in[4];
  // d_in[5] = bias: cancels under batch-stat BN
  const float* gamma = (const float*)d_in[6];
  const float* beta  = (const float*)d_in[7];

  int n = in_sizes[0] / 256;
  int E = in_sizes[1] / 2;
  int tot = E + n;
  const int* src = ei;
  const int* dstp = ei + E;
  float* out = (float*)d_out;

  int NB = (n + 255) / 256;
  int ntiles = (n + 63) / 64;

  char* p = (char*)d_ws;
  unsigned short* hb = (unsigned short*)p; p = align16(p + (size_t)n * 128 * 2);
  float* a_s   = (float*)p; p = align16(p + (size_t)n * 4 * 4);
  float* a_d   = (float*)p; p = align16(p + (size_t)n * 4 * 4);
  float* sums  = (float*)p; p = align16(p + 128 * 4);
  float* sumsq = (float*)p; p = align16(p + 128 * 4);
  float* scale = (float*)p; p = align16(p + 128 * 4);
  float* shift = (float*)p; p = align16(p + 128 * 4);
  int* deg     = (int*)p;   p = align16(p + (size_t)n * 4);
  int* off     = (int*)p;   p = align16(p + (size_t)(n + 1) * 4);
  int* cur     = (int*)p;   p = align16(p + (size_t)n * 4);
  int* bsum    = (int*)p;   p = align16(p + (size_t)NB * 4);
  int* ssrc    = (int*)p;   p = align16(p + (size_t)tot * 4);

  hipMemsetAsync(sums, 0, 2 * 128 * 4, stream);  // sums+sumsq contiguous
  hipMemsetAsync(deg, 0, (size_t)n * 4, stream);

  gemm_mfma<<<256, 256, 0, stream>>>(x, W, hb, n, ntiles);
  att_scores<<<(n + 3) / 4, 256, 0, stream>>>(hb, att_s, att_d, a_s, a_d, n);

  deg_count_k<<<(E + 255) / 256, 256, 0, stream>>>(dstp, deg, E);
  blocksum_k<<<NB, 256, 0, stream>>>(deg, bsum, n);
  scan_bsum_k<<<1, 1024, 0, stream>>>(bsum, NB);
  offsets_k<<<NB, 256, 0, stream>>>(deg, bsum, off, cur, n, tot);
  scatter_k<<<(tot + 255) / 256, 256, 0, stream>>>(src, dstp, cur, ssrc, E, n);

  agg_csr_k<<<(n + 3) / 4, 256, 0, stream>>>(off, ssrc, a_s, a_d, hb, out, n);

  bn_stats_k<<<256, 256, 0, stream>>>(out, sums, sumsq, n);
  bn_coef_k<<<1, 128, 0, stream>>>(sums, sumsq, gamma, beta, scale, shift, 1.0f / n);
  bn_apply_k<<<(n * 32 + 255) / 256, 256, 0, stream>>>(out, scale, shift, n * 32);
}